// Round 11
// baseline (108.035 us; speedup 1.0000x reference)
//
#include <hip/hip_runtime.h>

#define SGRID 14
static constexpr float INV_S = 1.0f / 14.0f;

__device__ __forceinline__ float cell_loss(const float* p, const float* t) {
    float tconf = t[4];
    float obj   = (tconf == 1.0f) ? 1.0f : 0.0f;
    float noobj = (tconf == 0.0f) ? 1.0f : 0.0f;

    float d4 = p[4] - t[4];
    float d9 = p[9] - t[9];
    float no_object_loss = noobj * (d4 * d4 + d9 * d9);

    float class_loss = 0.0f;
    #pragma unroll
    for (int c = 10; c < 30; ++c) { float d = p[c] - t[c]; class_loss += d * d; }
    class_loss *= obj;

    float iou[2];
    #pragma unroll
    for (int b = 0; b < 2; ++b) {
        int o = b * 5;
        float pcx = p[o] * INV_S, pcy = p[o+1] * INV_S, pw = p[o+2], ph = p[o+3];
        float tcx = t[o] * INV_S, tcy = t[o+1] * INV_S, tw = t[o+2], th = t[o+3];
        float px0 = pcx - 0.5f * pw, py0 = pcy - 0.5f * ph;
        float px1 = pcx + 0.5f * pw, py1 = pcy + 0.5f * ph;
        float tx0 = tcx - 0.5f * tw, ty0 = tcy - 0.5f * th;
        float tx1 = tcx + 0.5f * tw, ty1 = tcy + 0.5f * th;
        float lx = fmaxf(px0, tx0), ly = fmaxf(py0, ty0);
        float rx = fminf(px1, tx1), ry = fminf(py1, ty1);
        float wx = fmaxf(rx - lx, 0.0f), wy = fmaxf(ry - ly, 0.0f);
        float inter = wx * wy;
        float ap = (px1 - px0) * (py1 - py0);
        float at = (tx1 - tx0) * (ty1 - ty0);
        float denom = ap + at - inter;
        iou[b] = (denom > 0.0f) ? (inter / denom) : 0.0f;
    }

    bool pick1 = (iou[0] <= iou[1]);
    float chosen = pick1 ? iou[1] : iou[0];
    int o = pick1 ? 5 : 0;

    float dx = p[o]   - t[o];
    float dy = p[o+1] - t[o+1];
    float dw = sqrtf(p[o+2]) - sqrtf(t[o+2]);
    float dh = sqrtf(p[o+3]) - sqrtf(t[o+3]);
    float reg = dx * dx + dy * dy + dw * dw + dh * dh;

    float dconf = p[o+4] - chosen;
    float contain = dconf * dconf;

    return obj * (5.0f * reg + contain) + 0.5f * no_object_loss + class_loss;
}

// Barrier-free perpetual pipeline, race-fixed. 1-wave (64-thread) blocks,
// wave-private 15.36 KB LDS (one 64-cell chunk), SINGLE float4-packed reg set
// (dead after its ds_write -> no A/B needed). Per iteration:
//   1. issue next chunk's 16 coalesced loads (7xf4 + 1xf2 per tensor)
//   2. compute current chunk from LDS (loads in flight underneath)
//   3. ds_write regs -> LDS (per-reg vmcnt waits; mostly drained by now)
//   4. explicit lgkmcnt(0) + sched_barrier (cross-lane LDS RAW fence; the
//      R10 failure was relying on compiler AA for this ordering)
// 10 blocks/CU (LDS-capped) -> 10 independent streams, each keeping ~15 KB
// posted during most of its period; no block-wide sync anywhere.
__global__ __launch_bounds__(64) void yolo_loss_kernel(
    const float* __restrict__ pred, const float* __restrict__ tgt,
    float* __restrict__ out, int ncells, int nchunks, float invN)
{
    __shared__ float sbuf[3840];      // 15360 B: pred [0,1920), tgt [1920,3840)
    const int lane = threadIdx.x;     // 0..63
    const int stride = gridDim.x;
    float sum = 0.0f;

    float4 rp[7], rt[7];
    float2 rp2, rt2;

    auto loadset = [&](int c) {
        const float* pb = pred + (size_t)c * 1920;
        const float* tb = tgt  + (size_t)c * 1920;
        const float4* p4 = (const float4*)pb;
        const float4* t4 = (const float4*)tb;
        #pragma unroll
        for (int k = 0; k < 7; ++k) rp[k] = p4[k * 64 + lane];
        rp2 = ((const float2*)(pb + 1792))[lane];
        #pragma unroll
        for (int k = 0; k < 7; ++k) rt[k] = t4[k * 64 + lane];
        rt2 = ((const float2*)(tb + 1792))[lane];
    };

    auto store_fence = [&]() {
        asm volatile("" ::: "memory");            // keep prior ds_reads above
        float4* s4p = (float4*)sbuf;
        float4* s4t = (float4*)(sbuf + 1920);
        #pragma unroll
        for (int k = 0; k < 7; ++k) s4p[k * 64 + lane] = rp[k];
        ((float2*)(sbuf + 1792))[lane] = rp2;
        #pragma unroll
        for (int k = 0; k < 7; ++k) s4t[k * 64 + lane] = rt[k];
        ((float2*)(sbuf + 1920 + 1792))[lane] = rt2;
        asm volatile("s_waitcnt lgkmcnt(0)" ::: "memory");   // writes visible
        __builtin_amdgcn_sched_barrier(0);                   // rule #18 fence
    };

    int c = blockIdx.x;
    if (c < nchunks) {
        loadset(c);
        store_fence();
        for (;;) {
            int nc = c + stride;
            bool have = nc < nchunks;
            if (have) loadset(nc);     // next chunk posted during compute
            sum += cell_loss(sbuf + lane * 30, sbuf + 1920 + lane * 30);
            if (!have) break;
            store_fence();             // stage next; waits only its own loads
            c = nc;
        }
    }

    // remainder cells (ncells % 64) — direct global path, block 0 only
    int rem = ncells - nchunks * 64;
    if (rem > 0 && blockIdx.x == 0 && lane < rem) {
        int cell = nchunks * 64 + lane;
        const float2* p2 = (const float2*)(pred + (size_t)cell * 30);
        const float2* t2 = (const float2*)(tgt  + (size_t)cell * 30);
        float p[30], t[30];
        #pragma unroll
        for (int j = 0; j < 15; ++j) { float2 v = p2[j]; p[2*j] = v.x; p[2*j+1] = v.y; }
        #pragma unroll
        for (int j = 0; j < 15; ++j) { float2 v = t2[j]; t[2*j] = v.x; t[2*j+1] = v.y; }
        sum += cell_loss(p, t);
    }

    #pragma unroll
    for (int off = 32; off > 0; off >>= 1) sum += __shfl_down(sum, off, 64);
    if (lane == 0) atomicAdd(out, sum * invN);
}

extern "C" void kernel_launch(void* const* d_in, const int* in_sizes, int n_in,
                              void* d_out, int out_size, void* d_ws, size_t ws_size,
                              hipStream_t stream) {
    const float* pred = (const float*)d_in[0];
    const float* tgt  = (const float*)d_in[1];
    float* out = (float*)d_out;

    int ncells  = in_sizes[0] / 30;               // N * S * S
    int N       = ncells / (SGRID * SGRID);
    float invN  = 1.0f / (float)N;
    int nchunks = ncells / 64;

    hipMemsetAsync(out, 0, sizeof(float) * (out_size > 0 ? out_size : 1), stream);

    // 15.36 KB LDS -> 10 blocks/CU; 10 x 256 = 2560 resident blocks
    int blocks = nchunks < 1 ? 1 : (nchunks < 2560 ? nchunks : 2560);
    yolo_loss_kernel<<<blocks, 64, 0, stream>>>(pred, tgt, out, ncells, nchunks, invN);
}